// Round 3
// baseline (220.597 us; speedup 1.0000x reference)
//
#include <hip/hip_runtime.h>
#include <math.h>

#define DIM   1024
#define HEADS 16
#define DH    64
#define ROT   128
#define BATCH 2
#define SEQ   2048
#define ROWS  (BATCH*SEQ)        // 4096
#define PCOLS (DIM + 2*DH)       // 1152 = [q(1024) | k(64) | v(64)] per side
// 1/sqrt(128) * log2(e): scores arrive pre-scaled for exp2 in attn
#define ASCALE (0.08838834764831845f * 1.4426950408889634f)

typedef short bf16x8 __attribute__((ext_vector_type(8)));
typedef float f32x16 __attribute__((ext_vector_type(16)));
typedef unsigned u32x2 __attribute__((ext_vector_type(2)));

static __device__ __forceinline__ unsigned short f2bf(float f) {
    union { float f; unsigned u; } v; v.f = f;
    unsigned r = v.u + 0x7fffu + ((v.u >> 16) & 1u);   // RNE (no NaN inputs here)
    return (unsigned short)(r >> 16);
}
static __device__ __forceinline__ float bf2f(unsigned short u) {
    union { unsigned u; float f; } v; v.u = (unsigned)u << 16;
    return v.f;
}

#define GL2LDS(gp, lp) __builtin_amdgcn_global_load_lds(                    \
    (const __attribute__((address_space(1))) void*)(gp),                    \
    (__attribute__((address_space(3))) void*)(lp), 16, 0, 0)
#define CFENCE() asm volatile("" ::: "memory")
// s_waitcnt imm: vmcnt[3:0]|[15:14], expcnt[6:4], lgkmcnt[11:8]; others maxed
#define WAIT_VM8()  __builtin_amdgcn_s_waitcnt(0xF78)   // vmcnt(8)
#define WAIT_VM4()  __builtin_amdgcn_s_waitcnt(0xF74)   // vmcnt(4)
#define WAIT_VM0()  __builtin_amdgcn_s_waitcnt(0xF70)   // vmcnt(0)

// ---------------------------------------------------------------------------
// Convert fp32 inputs -> bf16 staging buffers + rotary cos/sin table.
// ---------------------------------------------------------------------------
__global__ __launch_bounds__(256) void convert_kernel(
    const float* __restrict__ x, const float* __restrict__ a,
    const float* __restrict__ Wq_x, const float* __restrict__ Wkv_x,
    const float* __restrict__ Wq_a, const float* __restrict__ Wkv_a,
    unsigned short* __restrict__ xbf, unsigned short* __restrict__ wbf,
    float2* __restrict__ tbl)
{
    const int blk = blockIdx.x;
    const float LN1E4_64 = 0.14391156831213f;   // ln(10000)/64
    if (blk >= 2624) {                           // rotary table segment
        int local = blk - 2624;                  // 0..127
        int pos = local * 16 + (threadIdx.x >> 4);
        int i   = threadIdx.x & 15;
        #pragma unroll
        for (int j = 0; j < 4; j++) {
            int jd = i * 4 + j;
            float th = (float)pos * expf(-LN1E4_64 * (float)jd);
            float sn, cs; sincosf(th, &sn, &cs);
            tbl[pos * 64 + jd] = make_float2(cs, sn);
        }
        return;
    }
    const float* s; unsigned short* d; int seg0;
    if      (blk < 1024) { s = x;     d = xbf;           seg0 = 0;    }
    else if (blk < 2048) { s = a;     d = xbf + 4194304; seg0 = 1024; }
    else if (blk < 2304) { s = Wq_x;  d = wbf;           seg0 = 2048; }
    else if (blk < 2336) { s = Wkv_x; d = wbf + 1048576; seg0 = 2304; }
    else if (blk < 2592) { s = Wq_a;  d = wbf + 1179648; seg0 = 2336; }
    else                 { s = Wkv_a; d = wbf + 2228224; seg0 = 2592; }
    long lb = ((long)blk - seg0) * 1024;
    #pragma unroll
    for (int j = 0; j < 4; j++) {
        long idx = lb + j * 256 + threadIdx.x;
        float4 v = ((const float4*)s)[idx];
        ((ushort4*)d)[idx] = make_ushort4(f2bf(v.x), f2bf(v.y), f2bf(v.z), f2bf(v.w));
    }
}

// ---------------------------------------------------------------------------
// MFMA GEMM (bf16, 32x32x16) — R5: double-buffered prefetch with counted
// vmcnt(4) + raw barriers (same proven pattern as attn_kernel).  The old
// stage->syncthreads(vmcnt0 drain)->compute exposed full L2 latency 32x.
// LDS layout (bytes): A0@0, A1@8192, B0@16384, B1@24576  (32 KB total).
// ---------------------------------------------------------------------------
__global__ __launch_bounds__(256) void mfma_gemm_kernel(
    const unsigned short* __restrict__ xbf, const unsigned short* __restrict__ wbf,
    unsigned short* __restrict__ Pbf)
{
    const int mt = blockIdx.x, jt = blockIdx.y, side = blockIdx.z;
    const unsigned short* Ag = xbf + ((size_t)side * ROWS  + mt * 128) * DIM;
    const unsigned short* Bg = wbf + ((size_t)side * PCOLS + jt * 128) * DIM;
    unsigned short* Pp = Pbf + (size_t)side * ROWS * PCOLS;

    __shared__ __align__(16) char scg[32768];

    const int tid  = threadIdx.x;
    const int wave = tid >> 6, lane = tid & 63;
    const int m = lane & 31, hl = lane >> 5;
    const int wr = wave >> 1, wc = wave & 1;

    f32x16 acc[2][2];
    #pragma unroll
    for (int i2 = 0; i2 < 2; i2++)
        #pragma unroll
        for (int j2 = 0; j2 < 2; j2++) acc[i2][j2] = 0.0f;

    // staging: s = it*256+tid -> row sr (64B), granule sg (16B, XOR-swizzled)
    const unsigned short* Asrc[2];
    const unsigned short* Bsrc[2];
    unsigned ldsb[2];
    #pragma unroll
    for (int it = 0; it < 2; it++) {
        int s = it * 256 + tid;
        int sr = s >> 2;
        int sg = (s & 3) ^ ((sr >> 1) & 3);
        Asrc[it] = Ag + (size_t)sr * DIM + sg * 8;
        Bsrc[it] = Bg + (size_t)sr * DIM + sg * 8;
        ldsb[it] = (unsigned)(it * 256 + wave * 64) * 16;
    }

    // read-side byte offsets (buf-0 base)
    unsigned aoff[2][2], boff[2][2];
    #pragma unroll
    for (int kp = 0; kp < 2; kp++)
        #pragma unroll
        for (int t2 = 0; t2 < 2; t2++) {
            int ra = wr * 64 + t2 * 32 + m;
            int ga = (kp * 2 + hl) ^ ((ra >> 1) & 3);
            aoff[kp][t2] = (unsigned)(ra * 64 + ga * 16);
            int rb = wc * 64 + t2 * 32 + m;
            int gb = (kp * 2 + hl) ^ ((rb >> 1) & 3);
            boff[kp][t2] = (unsigned)(rb * 64 + gb * 16);
        }

    // stage tile 0 into buffer 0
    #pragma unroll
    for (int it = 0; it < 2; it++) {
        GL2LDS(Asrc[it], scg + ldsb[it]);
        GL2LDS(Bsrc[it], scg + 16384 + ldsb[it]);
    }

#define GEMM_TILE(BUF, T)                                                          \
  {                                                                                \
    if ((T) < 31) {                       /* prefetch T+1 into alternate buffer */ \
      _Pragma("unroll")                                                            \
      for (int it = 0; it < 2; it++) {                                             \
        GL2LDS(Asrc[it] + ((T) + 1) * 32, scg + ((BUF) ^ 1) * 8192 + ldsb[it]);    \
        GL2LDS(Bsrc[it] + ((T) + 1) * 32,                                          \
               scg + 16384 + ((BUF) ^ 1) * 8192 + ldsb[it]);                       \
      }                                                                            \
    }                                                                              \
    CFENCE();                                                                      \
    if ((T) < 31) WAIT_VM4(); else WAIT_VM0();   /* tile T's 4 loads are oldest */ \
    __builtin_amdgcn_s_barrier();                                                  \
    CFENCE();                                                                      \
    _Pragma("unroll")                                                              \
    for (int kp = 0; kp < 2; kp++) {                                               \
      bf16x8 af[2], bff[2];                                                        \
      _Pragma("unroll")                                                            \
      for (int t2 = 0; t2 < 2; t2++) {                                             \
        af[t2]  = *(const bf16x8*)(scg + (BUF) * 8192 + aoff[kp][t2]);             \
        bff[t2] = *(const bf16x8*)(scg + 16384 + (BUF) * 8192 + boff[kp][t2]);     \
      }                                                                            \
      _Pragma("unroll")                                                            \
      for (int i2 = 0; i2 < 2; i2++)                                               \
        _Pragma("unroll")                                                          \
        for (int j2 = 0; j2 < 2; j2++)                                             \
          acc[i2][j2] = __builtin_amdgcn_mfma_f32_32x32x16_bf16(                   \
              af[i2], bff[j2], acc[i2][j2], 0, 0, 0);                              \
    }                                                                              \
    CFENCE();                                                                      \
    __builtin_amdgcn_s_barrier();   /* protect BUF from T+2's prefetch */          \
    CFENCE();                                                                      \
  }

    for (int tt = 0; tt < 32; tt += 2) {
        GEMM_TILE(0, tt);
        GEMM_TILE(1, tt + 1);
    }
#undef GEMM_TILE

    const int m0 = mt * 128 + wr * 64;
    const int n0 = jt * 128 + wc * 64;
    #pragma unroll
    for (int i2 = 0; i2 < 2; i2++)
        #pragma unroll
        for (int j2 = 0; j2 < 2; j2++)
            #pragma unroll
            for (int r = 0; r < 16; r++) {
                int row = m0 + i2 * 32 + (r & 3) + 8 * (r >> 2) + 4 * hl;
                int col = n0 + j2 * 32 + m;
                Pp[(size_t)row * PCOLS + col] = f2bf(acc[i2][j2][r]);
            }
}

// ---------------------------------------------------------------------------
// Fuse: l2norm + scale + concat + rotary (bf16 P in, table-driven rotary).
// R5: 8 rows per block (grid 4096 -> 512).  V^T goes through a 2 KB LDS
// transpose so the global store is one coalesced 16B write per d-row
// (vT[d][pos0..pos0+7]) instead of 4 scalar 2B stores at 4 KB stride.
// Q carries 1/sqrt(128)*log2(e) so attn can use raw v_exp_f32.
// ---------------------------------------------------------------------------
__global__ __launch_bounds__(256) void fuse_kernel(
    const unsigned short* __restrict__ Pbf,
    const float* __restrict__ qx_scale, const float* __restrict__ qa_scale,
    const float* __restrict__ kx_scale, const float* __restrict__ ka_scale,
    const float2* __restrict__ tbl,
    unsigned short* __restrict__ qbuf, unsigned short* __restrict__ kbuf,
    unsigned short* __restrict__ vbufT)
{
    const int blk = blockIdx.x;              // 0..511
    const int b = blk >> 8;                  // batch
    const int pos0 = (blk & 255) << 3;       // first of 8 rows
    __shared__ unsigned short Vs[8][128];
    const int tid = threadIdx.x;
    const int h = tid >> 4, i = tid & 15;

    for (int rr = 0; rr < 8; rr++) {
        const int pos = pos0 + rr;
        const int row = b * SEQ + pos;
        const unsigned short* Px = Pbf + (size_t)row * PCOLS;
        const unsigned short* Pa = Pbf + (size_t)ROWS * PCOLS + (size_t)row * PCOLS;
        const float2* tb = tbl + pos * 64;

        // ---- Q ----
        ushort4 xu = *(const ushort4*)(Px + h * DH + i * 4);
        ushort4 au = *(const ushort4*)(Pa + h * DH + i * 4);
        float xr[4] = {bf2f(xu.x), bf2f(xu.y), bf2f(xu.z), bf2f(xu.w)};
        float ar[4] = {bf2f(au.x), bf2f(au.y), bf2f(au.z), bf2f(au.w)};
        float ssx = xr[0]*xr[0] + xr[1]*xr[1] + xr[2]*xr[2] + xr[3]*xr[3];
        float ssa = ar[0]*ar[0] + ar[1]*ar[1] + ar[2]*ar[2] + ar[3]*ar[3];
        #pragma unroll
        for (int off = 1; off < 16; off <<= 1) {
            ssx += __shfl_xor(ssx, off, 16);
            ssa += __shfl_xor(ssa, off, 16);
        }
        float inx = 1.0f / fmaxf(sqrtf(ssx), 1e-12f);
        float ina = 1.0f / fmaxf(sqrtf(ssa), 1e-12f);
        unsigned short qlo[4], qhi[4];
        #pragma unroll
        for (int j = 0; j < 4; j++) {
            int jd = i * 4 + j;
            float qx = xr[j] * inx * qx_scale[h * DH + jd];
            float qa = ar[j] * ina * qa_scale[h * DH + jd];
            float2 cssn = tb[jd];
            qlo[j] = f2bf((qx * cssn.x - qa * cssn.y) * ASCALE);
            qhi[j] = f2bf((qa * cssn.x + qx * cssn.y) * ASCALE);
        }
        unsigned short* qp = qbuf + (((size_t)(b * HEADS + h)) * SEQ + pos) * ROT;
        *(ushort4*)(qp + i * 4)      = make_ushort4(qlo[0], qlo[1], qlo[2], qlo[3]);
        *(ushort4*)(qp + DH + i * 4) = make_ushort4(qhi[0], qhi[1], qhi[2], qhi[3]);

        // ---- K ----
        if (tid < 16) {
            ushort4 kxu = *(const ushort4*)(Px + DIM + tid * 4);
            ushort4 kau = *(const ushort4*)(Pa + DIM + tid * 4);
            float kxr[4] = {bf2f(kxu.x), bf2f(kxu.y), bf2f(kxu.z), bf2f(kxu.w)};
            float kar[4] = {bf2f(kau.x), bf2f(kau.y), bf2f(kau.z), bf2f(kau.w)};
            float sx = kxr[0]*kxr[0] + kxr[1]*kxr[1] + kxr[2]*kxr[2] + kxr[3]*kxr[3];
            float sa = kar[0]*kar[0] + kar[1]*kar[1] + kar[2]*kar[2] + kar[3]*kar[3];
            #pragma unroll
            for (int off = 1; off < 16; off <<= 1) {
                sx += __shfl_xor(sx, off, 16);
                sa += __shfl_xor(sa, off, 16);
            }
            float ikx = 1.0f / fmaxf(sqrtf(sx), 1e-12f);
            float ika = 1.0f / fmaxf(sqrtf(sa), 1e-12f);
            unsigned short klo[4], khi[4];
            #pragma unroll
            for (int j = 0; j < 4; j++) {
                int jd = tid * 4 + j;
                float kx = kxr[j] * ikx * kx_scale[jd];
                float ka = kar[j] * ika * ka_scale[jd];
                float2 cssn = tb[jd];
                klo[j] = f2bf(kx * cssn.x - ka * cssn.y);
                khi[j] = f2bf(ka * cssn.x + kx * cssn.y);
            }
            unsigned short* kp = kbuf + ((size_t)b * SEQ + pos) * ROT;
            *(ushort4*)(kp + tid * 4)      = make_ushort4(klo[0], klo[1], klo[2], klo[3]);
            *(ushort4*)(kp + DH + tid * 4) = make_ushort4(khi[0], khi[1], khi[2], khi[3]);
        }
        // ---- V (stage to LDS, exact bf16 copy) ----
        if (tid >= 64 && tid < 96) {
            int iv = tid - 64;
            const unsigned short* src; int d;
            if (iv < 16) { src = Px + DIM + DH + iv * 4;        d = iv * 4;              }
            else         { src = Pa + DIM + DH + (iv - 16) * 4; d = DH + (iv - 16) * 4;  }
            ushort4 v4 = *(const ushort4*)src;
            *(ushort4*)&Vs[rr][d] = v4;
        }
    }
    __syncthreads();
    // ---- V transposed write: one 16B store per d-row ----
    if (tid < 128) {
        const int d = tid;
        union { unsigned short u[8]; bf16x8 v; } pk;
        #pragma unroll
        for (int rr = 0; rr < 8; rr++) pk.u[rr] = Vs[rr][d];
        *(bf16x8*)(vbufT + (size_t)b * ROT * SEQ + (size_t)d * SEQ + pos0) = pk.v;
    }
}

// ---------------------------------------------------------------------------
// MFMA flash attention (bf16, 32x32x16), double-buffered pipeline.
// (unchanged from R4 — verified)
// Layout of smem (bytes): K0@0, K1@16384, V0@32768, V1@49152.
// ---------------------------------------------------------------------------
__global__ __launch_bounds__(256, 2) void attn_kernel(
    const unsigned short* __restrict__ qbuf,
    const unsigned short* __restrict__ kbuf,
    const unsigned short* __restrict__ vbufT,
    float* __restrict__ out)
{
    const int qb = blockIdx.x, h = blockIdx.y, b = blockIdx.z;
    __shared__ __align__(16) unsigned short smem[32768];   // 64 KB
    const char* sc = (const char*)smem;
    const int tid  = threadIdx.x;
    const int wave = tid >> 6, lane = tid & 63;
    const int m = lane & 31, hl = lane >> 5;
    const int q0 = qb * 128 + wave * 32;

    // Q resident (B-frag): chunk c covers d = c*16 + hl*8 + j
    bf16x8 qf[8];
    {
        const unsigned short* qp = qbuf + (((size_t)(b * HEADS + h)) * SEQ + q0 + m) * ROT + hl * 8;
        #pragma unroll
        for (int c = 0; c < 8; c++) qf[c] = *(const bf16x8*)(qp + c * 16);
    }

    f32x16 oacc[4];
    #pragma unroll
    for (int dt = 0; dt < 4; dt++) oacc[dt] = 0.0f;
    float lsum = 0.f;

    // Precomputed per-lane LDS byte offsets (buf=0, kg=0, dt=0 bases).
    unsigned koff[8];
    #pragma unroll
    for (int c = 0; c < 8; c++)
        koff[c] = (unsigned)(m * 256 + (((2 * c + hl) ^ (m & 15)) << 4));
    unsigned voff[2][2];
    #pragma unroll
    for (int kg = 0; kg < 2; kg++)
        #pragma unroll
        for (int w = 0; w < 2; w++)
            voff[kg][w] = (unsigned)(32768 + m * 128 +
                                     (((kg * 4 + w * 2 + hl) ^ ((m >> 2) & 7)) << 4));

    const unsigned short* kb_ = kbuf  + (size_t)b * SEQ * ROT;
    const unsigned short* vb_ = vbufT + (size_t)b * ROT * SEQ;

    // per-thread staging addresses (swizzle folded into the global source)
    const unsigned short* ksrc[4];
    const unsigned short* vsrc[4];
    unsigned ldst[4];
    #pragma unroll
    for (int i = 0; i < 4; i++) {
        int fg = i * 256 + tid;
        int krow = fg >> 4, kgr = fg & 15;                // K: 64 rows x 16 granules
        ksrc[i] = kb_ + (size_t)krow * ROT + ((kgr ^ (krow & 15)) << 3);
        int rv = fg >> 3, gv = fg & 7;                    // V^T: 128 rows x 8 granules
        vsrc[i] = vb_ + (size_t)rv * SEQ + ((gv ^ ((rv >> 2) & 7)) << 3);
        ldst[i] = (unsigned)(i * 256 + wave * 64) * 16;   // bytes, wave-uniform base
    }

    // stage tile 0 into buffer 0
    #pragma unroll
    for (int i = 0; i < 4; i++) {
        GL2LDS(ksrc[i], sc + ldst[i]);
        GL2LDS(vsrc[i], sc + 32768 + ldst[i]);
    }

#define ATTN_TILE(BUF, T)                                                            \
  {                                                                                  \
    if ((T) < 31) {                        /* prefetch T+1 into alternate buffer */  \
      _Pragma("unroll")                                                              \
      for (int i = 0; i < 4; i++) {                                                  \
        GL2LDS(ksrc[i] + (size_t)((T) + 1) * 64 * ROT,                               \
               sc + ((BUF) ^ 1) * 16384 + ldst[i]);                                  \
        GL2LDS(vsrc[i] + ((T) + 1) * 64,                                             \
               sc + 32768 + ((BUF) ^ 1) * 16384 + ldst[i]);                          \
      }                                                                              \
    }                                                                                \
    CFENCE();                                                                        \
    if ((T) < 31) WAIT_VM8(); else WAIT_VM0();  /* tile T's 8 loads are oldest */    \
    __builtin_amdgcn_s_barrier();                                                    \
    CFENCE();                                                                        \
    f32x16 st0 = 0.0f, st1 = 0.0f;                                                   \
    __builtin_amdgcn_s_setprio(1);                                                   \
    _Pragma("unroll")                                                                \
    for (int c = 0; c < 8; c++) {                                                    \
      bf16x8 a0 = *(const bf16x8*)(sc + (BUF) * 16384 + koff[c]);                    \
      st0 = __builtin_amdgcn_mfma_f32_32x32x16_bf16(a0, qf[c], st0, 0, 0, 0);        \
    }                                                                                \
    _Pragma("unroll")                                                                \
    for (int c = 0; c < 8; c++) {                                                    \
      bf16x8 a1 = *(const bf16x8*)(sc + (BUF) * 16384 + 8192 + koff[c]);             \
      st1 = __builtin_amdgcn_mfma_f32_32x32x16_bf16(a1, qf[c], st1, 0, 0, 0);        \
    }                                                                                \
    __builtin_amdgcn_s_setprio(0);                                                   \
    _Pragma("unroll")                                                                \
    for (int kg = 0; kg < 2; kg++) {                                                 \
      float p[16];                                                                   \
      _Pragma("unroll")                                                              \
      for (int r = 0; r < 16; r++) {                                                 \
        float sv = kg ? st1[r] : st0[r];                                             \
        p[r] = __builtin_amdgcn_exp2f(sv); lsum += p[r];                             \
      }                                                                              \
      __builtin_amdgcn_s_setprio(1);                                                 \
      _Pragma("unroll")                                                              \
      for (int w = 0; w < 2; w++) {                                                  \
        unsigned pk0, pk1, pk2, pk3;                                                 \
        asm("v_cvt_pk_bf16_f32 %0, %1, %2" : "=v"(pk0) : "v"(p[8*w+0]), "v"(p[8*w+1])); \
        asm("v_cvt_pk_bf16_f32 %0, %1, %2" : "=v"(pk1) : "v"(p[8*w+2]), "v"(p[8*w+3])); \
        asm("v_cvt_pk_bf16_f32 %0, %1, %2" : "=v"(pk2) : "v"(p[8*w+4]), "v"(p[8*w+5])); \
        asm("v_cvt_pk_bf16_f32 %0, %1, %2" : "=v"(pk3) : "v"(p[8*w+6]), "v"(p[8*w+7])); \
        u32x2 s0 = __builtin_amdgcn_permlane32_swap(pk0, pk2, false, false);         \
        u32x2 s1 = __builtin_amdgcn_permlane32_swap(pk1, pk3, false, false);         \
        union { unsigned u[4]; bf16x8 v; } apu;                                      \
        apu.u[0] = s0[0]; apu.u[1] = s1[0]; apu.u[2] = s0[1]; apu.u[3] = s1[1];      \
        bf16x8 aP = apu.v;                                                           \
        _Pragma("unroll")                                                            \
        for (int dt = 0; dt < 4; dt++) {                                             \
          bf16x8 vf = *(const bf16x8*)(sc + (BUF) * 16384 + voff[kg][w] + dt * 4096);\
          oacc[dt] = __builtin_amdgcn_mfma_f32_32x32x16_bf16(aP, vf, oacc[dt], 0, 0, 0); \
        }                                                                            \
      }                                                                              \
      __builtin_amdgcn_s_setprio(0);                                                 \
    }                                                                                \
    CFENCE();                                                                        \
    __builtin_amdgcn_s_barrier();   /* protect buf from T+2's prefetch overwrite */  \
    CFENCE();                                                                        \
  }

    for (int tt = 0; tt < 32; tt += 2) {
        ATTN_TILE(0, tt);
        ATTN_TILE(1, tt + 1);
    }
#undef ATTN_TILE

    lsum += __shfl_xor(lsum, 32);    // add other half-lane's keys
    float* ob = out + ((size_t)(b * SEQ + q0)) * (HEADS * ROT) + h * ROT + m;
    #pragma unroll
    for (int r = 0; r < 16; r++) {
        int qrow = (r & 3) + 8 * (r >> 2) + 4 * hl;
        float linv = 1.0f / __shfl(lsum, qrow);
        float* orow = ob + (size_t)qrow * (HEADS * ROT);
        #pragma unroll
        for (int dt = 0; dt < 4; dt++) orow[dt * 32] = oacc[dt][r] * linv;
    }
}

// ---------------------------------------------------------------------------
extern "C" void kernel_launch(void* const* d_in, const int* in_sizes, int n_in,
                              void* d_out, int out_size, void* d_ws, size_t ws_size,
                              hipStream_t stream) {
    (void)in_sizes; (void)n_in; (void)out_size; (void)ws_size;
    const float* x        = (const float*)d_in[0];
    const float* a        = (const float*)d_in[1];
    const float* Wq_x     = (const float*)d_in[2];
    const float* Wkv_x    = (const float*)d_in[3];
    const float* Wq_a     = (const float*)d_in[4];
    const float* Wkv_a    = (const float*)d_in[5];
    const float* qx_scale = (const float*)d_in[6];
    const float* qa_scale = (const float*)d_in[7];
    const float* kx_scale = (const float*)d_in[8];
    const float* ka_scale = (const float*)d_in[9];
    float* out = (float*)d_out;

    unsigned short* Pbf   = (unsigned short*)d_ws;
    unsigned short* qbuf  = Pbf   + (size_t)2 * ROWS * PCOLS;
    unsigned short* kbuf  = qbuf  + (size_t)BATCH * HEADS * SEQ * ROT;
    unsigned short* vbufT = kbuf  + (size_t)BATCH * SEQ * ROT;
    unsigned short* xbf   = vbufT + (size_t)BATCH * SEQ * ROT;
    unsigned short* wbf   = xbf   + (size_t)2 * ROWS * DIM;
    float2*         tbl   = (float2*)(wbf + (size_t)2 * PCOLS * DIM);

    convert_kernel<<<dim3(2752), 256, 0, stream>>>(x, a, Wq_x, Wkv_x, Wq_a, Wkv_a,
                                                   xbf, wbf, tbl);
    mfma_gemm_kernel<<<dim3(32, 9, 2), 256, 0, stream>>>(xbf, wbf, Pbf);
    fuse_kernel<<<dim3(ROWS / 8), 256, 0, stream>>>(Pbf, qx_scale, qa_scale, kx_scale, ka_scale,
                                                    tbl, qbuf, kbuf, vbufT);
    attn_kernel<<<dim3(SEQ / 128, HEADS, BATCH), 256, 0, stream>>>(qbuf, kbuf, vbufT, out);
}

// Round 4
// 216.988 us; speedup vs baseline: 1.0166x; 1.0166x over previous
//
#include <hip/hip_runtime.h>
#include <math.h>

#define DIM   1024
#define HEADS 16
#define DH    64
#define ROT   128
#define BATCH 2
#define SEQ   2048
#define ROWS  (BATCH*SEQ)        // 4096
#define PCOLS (DIM + 2*DH)       // 1152 = [q(1024) | k(64) | v(64)] per side
// 1/sqrt(128) * log2(e): scores arrive pre-scaled for exp2 in attn
#define ASCALE (0.08838834764831845f * 1.4426950408889634f)

typedef short bf16x8 __attribute__((ext_vector_type(8)));
typedef float f32x16 __attribute__((ext_vector_type(16)));
typedef unsigned u32x2 __attribute__((ext_vector_type(2)));

static __device__ __forceinline__ unsigned short f2bf(float f) {
    union { float f; unsigned u; } v; v.f = f;
    unsigned r = v.u + 0x7fffu + ((v.u >> 16) & 1u);   // RNE (no NaN inputs here)
    return (unsigned short)(r >> 16);
}
static __device__ __forceinline__ float bf2f(unsigned short u) {
    union { unsigned u; float f; } v; v.u = (unsigned)u << 16;
    return v.f;
}

#define GL2LDS(gp, lp) __builtin_amdgcn_global_load_lds(                    \
    (const __attribute__((address_space(1))) void*)(gp),                    \
    (__attribute__((address_space(3))) void*)(lp), 16, 0, 0)
#define CFENCE() asm volatile("" ::: "memory")
#define WAIT_VM0()  __builtin_amdgcn_s_waitcnt(0xF70)   // vmcnt(0)

// ---------------------------------------------------------------------------
// Convert fp32 inputs -> bf16 staging buffers + rotary cos/sin table.
// ---------------------------------------------------------------------------
__global__ __launch_bounds__(256) void convert_kernel(
    const float* __restrict__ x, const float* __restrict__ a,
    const float* __restrict__ Wq_x, const float* __restrict__ Wkv_x,
    const float* __restrict__ Wq_a, const float* __restrict__ Wkv_a,
    unsigned short* __restrict__ xbf, unsigned short* __restrict__ wbf,
    float2* __restrict__ tbl)
{
    const int blk = blockIdx.x;
    const float LN1E4_64 = 0.14391156831213f;   // ln(10000)/64
    if (blk >= 2624) {                           // rotary table segment
        int local = blk - 2624;                  // 0..127
        int pos = local * 16 + (threadIdx.x >> 4);
        int i   = threadIdx.x & 15;
        #pragma unroll
        for (int j = 0; j < 4; j++) {
            int jd = i * 4 + j;
            float th = (float)pos * expf(-LN1E4_64 * (float)jd);
            float sn, cs; sincosf(th, &sn, &cs);
            tbl[pos * 64 + jd] = make_float2(cs, sn);
        }
        return;
    }
    const float* s; unsigned short* d; int seg0;
    if      (blk < 1024) { s = x;     d = xbf;           seg0 = 0;    }
    else if (blk < 2048) { s = a;     d = xbf + 4194304; seg0 = 1024; }
    else if (blk < 2304) { s = Wq_x;  d = wbf;           seg0 = 2048; }
    else if (blk < 2336) { s = Wkv_x; d = wbf + 1048576; seg0 = 2304; }
    else if (blk < 2592) { s = Wq_a;  d = wbf + 1179648; seg0 = 2336; }
    else                 { s = Wkv_a; d = wbf + 2228224; seg0 = 2592; }
    long lb = ((long)blk - seg0) * 1024;
    #pragma unroll
    for (int j = 0; j < 4; j++) {
        long idx = lb + j * 256 + threadIdx.x;
        float4 v = ((const float4*)s)[idx];
        ((ushort4*)d)[idx] = make_ushort4(f2bf(v.x), f2bf(v.y), f2bf(v.z), f2bf(v.w));
    }
}

// ---------------------------------------------------------------------------
// Fused GEMM + l2norm + scale + concat + rotary (R6).
// Grid (mt=32, jt=9), 512 threads = 8 waves (wr in [0,4): 32-token groups,
// wc in [0,2): 64-col halves).  Both sides computed in-block (acc0 = x-side,
// acc1 = a-side), so rotary's cross-side pairing is lane-local.  A 128-col
// jt tile aligns with head boundaries: each wave's 64 cols = one head's 64
// dims -> l2norm is an in-wave reduce (2 frags + 5 shfl_xor over m-lanes).
// Writes qbuf/kbuf/vbufT directly: fuse_kernel and the 38 MB Pbf round-trip
// are deleted.  Single barrier per K-tile: prefetch issued AFTER the
// barrier, so "all waves passed" already protects the overwritten buffer.
// LDS (bytes): A0@0, A1@8192, B0@16384, B1@24576 (32 KB).
// Tile tau in [0,64): side = tau>>5, k0 = (tau&31)*32.
// ---------------------------------------------------------------------------
__global__ __launch_bounds__(512) void gemm_fuse_kernel(
    const unsigned short* __restrict__ xbf, const unsigned short* __restrict__ wbf,
    const float* __restrict__ qx_scale, const float* __restrict__ qa_scale,
    const float* __restrict__ kx_scale, const float* __restrict__ ka_scale,
    const float2* __restrict__ tbl,
    unsigned short* __restrict__ qbuf, unsigned short* __restrict__ kbuf,
    unsigned short* __restrict__ vbufT)
{
    const int mt = blockIdx.x, jt = blockIdx.y;
    __shared__ __align__(16) char scg[32768];
    const int tid  = threadIdx.x;
    const int wave = tid >> 6, lane = tid & 63;
    const int m = lane & 31, hl = lane >> 5;
    const int wr = wave >> 1, wc = wave & 1;

    f32x16 acc0[2], acc1[2];
    acc0[0] = 0.0f; acc0[1] = 0.0f; acc1[0] = 0.0f; acc1[1] = 0.0f;

    // staging: thread tid -> row = tid>>2 (128 rows x 64B), granule tid&3,
    // source granule pre-XOR-swizzled.  One GL2LDS each for A and B per tile.
    const int srow = tid >> 2;
    const int sg   = (tid & 3) ^ ((srow >> 1) & 3);
    const unsigned short* Asrc = xbf + (size_t)mt * 128 * DIM + (size_t)srow * DIM + sg * 8;
    const unsigned short* Bsrc = wbf + (size_t)jt * 128 * DIM + (size_t)srow * DIM + sg * 8;
    const unsigned ldsw = (unsigned)wave * 1024;   // wave-uniform LDS base

    // read-side byte offsets
    const int ra = wr * 32 + m;
    unsigned aoff[2], boff[2][2];
    #pragma unroll
    for (int kp = 0; kp < 2; kp++) {
        aoff[kp] = (unsigned)(ra * 64 + (((kp * 2 + hl) ^ ((ra >> 1) & 3)) << 4));
        #pragma unroll
        for (int j2 = 0; j2 < 2; j2++) {
            int rb = wc * 64 + j2 * 32 + m;
            boff[kp][j2] = (unsigned)(rb * 64 + (((kp * 2 + hl) ^ ((rb >> 1) & 3)) << 4));
        }
    }

    // stage tile 0 (side 0, k0 = 0) into buffer 0
    GL2LDS(Asrc, scg + ldsw);
    GL2LDS(Bsrc, scg + 16384 + ldsw);

#define GEMM_STEP(ACC, BUF, T)                                                   \
  {                                                                              \
    CFENCE();                                                                    \
    WAIT_VM0();                                                                  \
    __builtin_amdgcn_s_barrier();                                                \
    CFENCE();                                                                    \
    if ((T) < 63) {                                                              \
      const int nt = (T) + 1;                                                    \
      const size_t so = (size_t)(nt >> 5);                                       \
      const int kk = (nt & 31) * 32;                                             \
      GL2LDS(Asrc + so * ((size_t)ROWS * DIM) + kk,                              \
             scg + ((BUF) ^ 1) * 8192 + ldsw);                                   \
      GL2LDS(Bsrc + so * ((size_t)PCOLS * DIM) + kk,                             \
             scg + 16384 + ((BUF) ^ 1) * 8192 + ldsw);                           \
    }                                                                            \
    CFENCE();                                                                    \
    _Pragma("unroll")                                                            \
    for (int kp = 0; kp < 2; kp++) {                                             \
      bf16x8 af = *(const bf16x8*)(scg + (BUF) * 8192 + aoff[kp]);               \
      bf16x8 b0 = *(const bf16x8*)(scg + 16384 + (BUF) * 8192 + boff[kp][0]);    \
      bf16x8 b1 = *(const bf16x8*)(scg + 16384 + (BUF) * 8192 + boff[kp][1]);    \
      ACC[0] = __builtin_amdgcn_mfma_f32_32x32x16_bf16(af, b0, ACC[0], 0, 0, 0); \
      ACC[1] = __builtin_amdgcn_mfma_f32_32x32x16_bf16(af, b1, ACC[1], 0, 0, 0); \
    }                                                                            \
  }

    for (int tt = 0; tt < 32; tt += 2) { GEMM_STEP(acc0, 0, tt); GEMM_STEP(acc0, 1, tt + 1); }
    for (int tt = 32; tt < 64; tt += 2) { GEMM_STEP(acc1, 0, tt); GEMM_STEP(acc1, 1, tt + 1); }
#undef GEMM_STEP

    // ---------------- epilogue: norm + scale + rotary + store -------------
    const int rowbase = mt * 128 + wr * 32;
    const int bb = rowbase >> 11;            // batch, block-uniform

    if (jt < 8) {
        // ---- Q: head h = jt*2 + wc, dims d = j2*32 + m ----
        const int h = jt * 2 + wc;
        const float scx0 = qx_scale[h * DH + m], scx1 = qx_scale[h * DH + 32 + m];
        const float sca0 = qa_scale[h * DH + m], sca1 = qa_scale[h * DH + 32 + m];
        unsigned short* qbase = qbuf + ((size_t)(bb * HEADS + h)) * SEQ * ROT;
        #pragma unroll
        for (int r = 0; r < 16; r++) {
            float px = acc0[0][r] * acc0[0][r] + acc0[1][r] * acc0[1][r];
            float pa = acc1[0][r] * acc1[0][r] + acc1[1][r] * acc1[1][r];
            #pragma unroll
            for (int off = 1; off < 32; off <<= 1) {
                px += __shfl_xor(px, off);
                pa += __shfl_xor(pa, off);
            }
            float inx = 1.0f / fmaxf(sqrtf(px), 1e-12f);
            float ina = 1.0f / fmaxf(sqrtf(pa), 1e-12f);
            const int row = rowbase + (r & 3) + 8 * (r >> 2) + 4 * hl;
            const int pos = row & 2047;
            const float2* tp = tbl + pos * 64;
            unsigned short* qrow = qbase + (size_t)pos * ROT;
            #pragma unroll
            for (int j2 = 0; j2 < 2; j2++) {
                const int d = j2 * 32 + m;
                float qx = acc0[j2][r] * inx * (j2 ? scx1 : scx0);
                float qa = acc1[j2][r] * ina * (j2 ? sca1 : sca0);
                float2 cs = tp[d];
                qrow[d]      = f2bf((qx * cs.x - qa * cs.y) * ASCALE);
                qrow[DH + d] = f2bf((qa * cs.x + qx * cs.y) * ASCALE);
            }
        }
    } else if (wc == 0) {
        // ---- K: dims d = j2*32 + m, shared scale, no ASCALE ----
        const float scx0 = kx_scale[m], scx1 = kx_scale[32 + m];
        const float sca0 = ka_scale[m], sca1 = ka_scale[32 + m];
        unsigned short* kbase = kbuf + (size_t)bb * SEQ * ROT;
        #pragma unroll
        for (int r = 0; r < 16; r++) {
            float px = acc0[0][r] * acc0[0][r] + acc0[1][r] * acc0[1][r];
            float pa = acc1[0][r] * acc1[0][r] + acc1[1][r] * acc1[1][r];
            #pragma unroll
            for (int off = 1; off < 32; off <<= 1) {
                px += __shfl_xor(px, off);
                pa += __shfl_xor(pa, off);
            }
            float inx = 1.0f / fmaxf(sqrtf(px), 1e-12f);
            float ina = 1.0f / fmaxf(sqrtf(pa), 1e-12f);
            const int row = rowbase + (r & 3) + 8 * (r >> 2) + 4 * hl;
            const int pos = row & 2047;
            const float2* tp = tbl + pos * 64;
            unsigned short* krow = kbase + (size_t)pos * ROT;
            #pragma unroll
            for (int j2 = 0; j2 < 2; j2++) {
                const int d = j2 * 32 + m;
                float kx = acc0[j2][r] * inx * (j2 ? scx1 : scx0);
                float ka = acc1[j2][r] * ina * (j2 ? sca1 : sca0);
                float2 cs = tp[d];
                krow[d]      = f2bf(kx * cs.x - ka * cs.y);
                krow[DH + d] = f2bf(ka * cs.x + kx * cs.y);
            }
        }
    } else {
        // ---- V: exact bf16 copy, transposed store (x-side d<64, a-side d>=64)
        unsigned short* vb = vbufT + (size_t)bb * ROT * SEQ;
        #pragma unroll
        for (int r = 0; r < 16; r++) {
            const int row = rowbase + (r & 3) + 8 * (r >> 2) + 4 * hl;
            const int pos = row & 2047;
            #pragma unroll
            for (int j2 = 0; j2 < 2; j2++) {
                const int d = j2 * 32 + m;
                vb[(size_t)d * SEQ + pos]        = f2bf(acc0[j2][r]);
                vb[(size_t)(DH + d) * SEQ + pos] = f2bf(acc1[j2][r]);
            }
        }
    }
}

// ---------------------------------------------------------------------------
// MFMA flash attention (bf16, 32x32x16), double-buffered pipeline.
// R6: single barrier per tile — prefetch issued AFTER the barrier (all waves
// past the barrier proves the alternate buffer's readers are done), so the
// trailing protect-barrier is deleted.  Loads issued at tile t land during
// compute(t), so the vmcnt(0) at tile t+1 is near-free.
// Layout of smem (bytes): K0@0, K1@16384, V0@32768, V1@49152.
// ---------------------------------------------------------------------------
__global__ __launch_bounds__(256, 2) void attn_kernel(
    const unsigned short* __restrict__ qbuf,
    const unsigned short* __restrict__ kbuf,
    const unsigned short* __restrict__ vbufT,
    float* __restrict__ out)
{
    const int qb = blockIdx.x, h = blockIdx.y, b = blockIdx.z;
    __shared__ __align__(16) unsigned short smem[32768];   // 64 KB
    const char* sc = (const char*)smem;
    const int tid  = threadIdx.x;
    const int wave = tid >> 6, lane = tid & 63;
    const int m = lane & 31, hl = lane >> 5;
    const int q0 = qb * 128 + wave * 32;

    // Q resident (B-frag): chunk c covers d = c*16 + hl*8 + j
    bf16x8 qf[8];
    {
        const unsigned short* qp = qbuf + (((size_t)(b * HEADS + h)) * SEQ + q0 + m) * ROT + hl * 8;
        #pragma unroll
        for (int c = 0; c < 8; c++) qf[c] = *(const bf16x8*)(qp + c * 16);
    }

    f32x16 oacc[4];
    #pragma unroll
    for (int dt = 0; dt < 4; dt++) oacc[dt] = 0.0f;
    float lsum = 0.f;

    // Precomputed per-lane LDS byte offsets (buf=0, kg=0, dt=0 bases).
    unsigned koff[8];
    #pragma unroll
    for (int c = 0; c < 8; c++)
        koff[c] = (unsigned)(m * 256 + (((2 * c + hl) ^ (m & 15)) << 4));
    unsigned voff[2][2];
    #pragma unroll
    for (int kg = 0; kg < 2; kg++)
        #pragma unroll
        for (int w = 0; w < 2; w++)
            voff[kg][w] = (unsigned)(32768 + m * 128 +
                                     (((kg * 4 + w * 2 + hl) ^ ((m >> 2) & 7)) << 4));

    const unsigned short* kb_ = kbuf  + (size_t)b * SEQ * ROT;
    const unsigned short* vb_ = vbufT + (size_t)b * ROT * SEQ;

    // per-thread staging addresses (swizzle folded into the global source)
    const unsigned short* ksrc[4];
    const unsigned short* vsrc[4];
    unsigned ldst[4];
    #pragma unroll
    for (int i = 0; i < 4; i++) {
        int fg = i * 256 + tid;
        int krow = fg >> 4, kgr = fg & 15;                // K: 64 rows x 16 granules
        ksrc[i] = kb_ + (size_t)krow * ROT + ((kgr ^ (krow & 15)) << 3);
        int rv = fg >> 3, gv = fg & 7;                    // V^T: 128 rows x 8 granules
        vsrc[i] = vb_ + (size_t)rv * SEQ + ((gv ^ ((rv >> 2) & 7)) << 3);
        ldst[i] = (unsigned)(i * 256 + wave * 64) * 16;   // bytes, wave-uniform base
    }

    // stage tile 0 into buffer 0
    #pragma unroll
    for (int i = 0; i < 4; i++) {
        GL2LDS(ksrc[i], sc + ldst[i]);
        GL2LDS(vsrc[i], sc + 32768 + ldst[i]);
    }

#define ATTN_TILE(BUF, T)                                                            \
  {                                                                                  \
    CFENCE();                                                                        \
    WAIT_VM0();                                                                      \
    __builtin_amdgcn_s_barrier();                                                    \
    CFENCE();                                                                        \
    if ((T) < 31) {                        /* prefetch T+1 into alternate buffer */  \
      _Pragma("unroll")                                                              \
      for (int i = 0; i < 4; i++) {                                                  \
        GL2LDS(ksrc[i] + (size_t)((T) + 1) * 64 * ROT,                               \
               sc + ((BUF) ^ 1) * 16384 + ldst[i]);                                  \
        GL2LDS(vsrc[i] + ((T) + 1) * 64,                                             \
               sc + 32768 + ((BUF) ^ 1) * 16384 + ldst[i]);                          \
      }                                                                              \
    }                                                                                \
    CFENCE();                                                                        \
    f32x16 st0 = 0.0f, st1 = 0.0f;                                                   \
    __builtin_amdgcn_s_setprio(1);                                                   \
    _Pragma("unroll")                                                                \
    for (int c = 0; c < 8; c++) {                                                    \
      bf16x8 a0 = *(const bf16x8*)(sc + (BUF) * 16384 + koff[c]);                    \
      st0 = __builtin_amdgcn_mfma_f32_32x32x16_bf16(a0, qf[c], st0, 0, 0, 0);        \
    }                                                                                \
    _Pragma("unroll")                                                                \
    for (int c = 0; c < 8; c++) {                                                    \
      bf16x8 a1 = *(const bf16x8*)(sc + (BUF) * 16384 + 8192 + koff[c]);             \
      st1 = __builtin_amdgcn_mfma_f32_32x32x16_bf16(a1, qf[c], st1, 0, 0, 0);        \
    }                                                                                \
    __builtin_amdgcn_s_setprio(0);                                                   \
    _Pragma("unroll")                                                                \
    for (int kg = 0; kg < 2; kg++) {                                                 \
      float p[16];                                                                   \
      _Pragma("unroll")                                                              \
      for (int r = 0; r < 16; r++) {                                                 \
        float sv = kg ? st1[r] : st0[r];                                             \
        p[r] = __builtin_amdgcn_exp2f(sv); lsum += p[r];                             \
      }                                                                              \
      __builtin_amdgcn_s_setprio(1);                                                 \
      _Pragma("unroll")                                                              \
      for (int w = 0; w < 2; w++) {                                                  \
        unsigned pk0, pk1, pk2, pk3;                                                 \
        asm("v_cvt_pk_bf16_f32 %0, %1, %2" : "=v"(pk0) : "v"(p[8*w+0]), "v"(p[8*w+1])); \
        asm("v_cvt_pk_bf16_f32 %0, %1, %2" : "=v"(pk1) : "v"(p[8*w+2]), "v"(p[8*w+3])); \
        asm("v_cvt_pk_bf16_f32 %0, %1, %2" : "=v"(pk2) : "v"(p[8*w+4]), "v"(p[8*w+5])); \
        asm("v_cvt_pk_bf16_f32 %0, %1, %2" : "=v"(pk3) : "v"(p[8*w+6]), "v"(p[8*w+7])); \
        u32x2 s0 = __builtin_amdgcn_permlane32_swap(pk0, pk2, false, false);         \
        u32x2 s1 = __builtin_amdgcn_permlane32_swap(pk1, pk3, false, false);         \
        union { unsigned u[4]; bf16x8 v; } apu;                                      \
        apu.u[0] = s0[0]; apu.u[1] = s1[0]; apu.u[2] = s0[1]; apu.u[3] = s1[1];      \
        bf16x8 aP = apu.v;                                                           \
        _Pragma("unroll")                                                            \
        for (int dt = 0; dt < 4; dt++) {                                             \
          bf16x8 vf = *(const bf16x8*)(sc + (BUF) * 16384 + voff[kg][w] + dt * 4096);\
          oacc[dt] = __builtin_amdgcn_mfma_f32_32x32x16_bf16(aP, vf, oacc[dt], 0, 0, 0); \
        }                                                                            \
      }                                                                              \
      __builtin_amdgcn_s_setprio(0);                                                 \
    }                                                                                \
  }

    for (int tt = 0; tt < 32; tt += 2) {
        ATTN_TILE(0, tt);
        ATTN_TILE(1, tt + 1);
    }
#undef ATTN_TILE

    lsum += __shfl_xor(lsum, 32);    // add other half-lane's keys
    float* ob = out + ((size_t)(b * SEQ + q0)) * (HEADS * ROT) + h * ROT + m;
    #pragma unroll
    for (int r = 0; r < 16; r++) {
        int qrow = (r & 3) + 8 * (r >> 2) + 4 * hl;
        float linv = 1.0f / __shfl(lsum, qrow);
        float* orow = ob + (size_t)qrow * (HEADS * ROT);
        #pragma unroll
        for (int dt = 0; dt < 4; dt++) orow[dt * 32] = oacc[dt][r] * linv;
    }
}

// ---------------------------------------------------------------------------
extern "C" void kernel_launch(void* const* d_in, const int* in_sizes, int n_in,
                              void* d_out, int out_size, void* d_ws, size_t ws_size,
                              hipStream_t stream) {
    (void)in_sizes; (void)n_in; (void)out_size; (void)ws_size;
    const float* x        = (const float*)d_in[0];
    const float* a        = (const float*)d_in[1];
    const float* Wq_x     = (const float*)d_in[2];
    const float* Wkv_x    = (const float*)d_in[3];
    const float* Wq_a     = (const float*)d_in[4];
    const float* Wkv_a    = (const float*)d_in[5];
    const float* qx_scale = (const float*)d_in[6];
    const float* qa_scale = (const float*)d_in[7];
    const float* kx_scale = (const float*)d_in[8];
    const float* ka_scale = (const float*)d_in[9];
    float* out = (float*)d_out;

    // workspace layout kept from prior rounds (Pbf region now unused)
    unsigned short* Pbf   = (unsigned short*)d_ws;
    unsigned short* qbuf  = Pbf   + (size_t)2 * ROWS * PCOLS;
    unsigned short* kbuf  = qbuf  + (size_t)BATCH * HEADS * SEQ * ROT;
    unsigned short* vbufT = kbuf  + (size_t)BATCH * SEQ * ROT;
    unsigned short* xbf   = vbufT + (size_t)BATCH * SEQ * ROT;
    unsigned short* wbf   = xbf   + (size_t)2 * ROWS * DIM;
    float2*         tbl   = (float2*)(wbf + (size_t)2 * PCOLS * DIM);

    convert_kernel<<<dim3(2752), 256, 0, stream>>>(x, a, Wq_x, Wkv_x, Wq_a, Wkv_a,
                                                   xbf, wbf, tbl);
    gemm_fuse_kernel<<<dim3(32, 9), 512, 0, stream>>>(xbf, wbf,
                                                      qx_scale, qa_scale, kx_scale, ka_scale,
                                                      tbl, qbuf, kbuf, vbufT);
    attn_kernel<<<dim3(SEQ / 128, HEADS, BATCH), 256, 0, stream>>>(qbuf, kbuf, vbufT, out);
}